// Round 3
// baseline (1125.796 us; speedup 1.0000x reference)
//
#include <hip/hip_runtime.h>
#include <stdint.h>

#define B_   8
#define T_   2048
#define D_   1024
#define DFF_ 4096
#define M_   (B_ * T_)   // 16384

typedef __bf16 bf16;
typedef bf16  bf16x8 __attribute__((ext_vector_type(8)));
typedef bf16  bf16x4 __attribute__((ext_vector_type(4)));
typedef float f32x4  __attribute__((ext_vector_type(4)));

#define CAST_LDS(p) ((__attribute__((address_space(3))) void*)(p))
#define CAST_GLB(p) ((const __attribute__((address_space(1))) void*)(p))

// ---------------------------------------------------------------------------
// Fused fp32 -> bf16 convert for all 7 weight tensors (one launch).
// ---------------------------------------------------------------------------
struct CvtArgs {
    const float* s[7];
    bf16* d[7];
    int nblk[7];   // cumulative block offsets (exclusive end)
};

__global__ __launch_bounds__(256) void f2bf_all_kernel(CvtArgs a) {
    int blk = blockIdx.x;
    int seg = 0;
#pragma unroll
    for (int i = 0; i < 7; ++i) seg += (blk >= a.nblk[i]) ? 1 : 0;
    const int base = (seg == 0) ? 0 : a.nblk[seg - 1];
    const int i = ((blk - base) * 256 + threadIdx.x) * 4;
    const float4 v = *(const float4*)(a.s[seg] + i);
    bf16x4 o;
    o[0] = (bf16)v.x; o[1] = (bf16)v.y; o[2] = (bf16)v.z; o[3] = (bf16)v.w;
    *(bf16x4*)(a.d[seg] + i) = o;
}

// ---------------------------------------------------------------------------
// RMSNorm (one block per row, D=1024, 256 threads x float4) -> bf16 out
// ---------------------------------------------------------------------------
__global__ __launch_bounds__(256) void rmsnorm_kernel(const float* __restrict__ x,
                                                      const float* __restrict__ w,
                                                      bf16* __restrict__ y) {
    const size_t row = blockIdx.x;
    const int t = threadIdx.x;
    const float4 v = ((const float4*)(x + row * D_))[t];
    float ss = v.x * v.x + v.y * v.y + v.z * v.z + v.w * v.w;
#pragma unroll
    for (int off = 32; off; off >>= 1) ss += __shfl_down(ss, off);
    __shared__ float red[4];
    if ((t & 63) == 0) red[t >> 6] = ss;
    __syncthreads();
    const float total = red[0] + red[1] + red[2] + red[3];
    const float rstd = rsqrtf(total * (1.0f / (float)D_) + 1e-6f);
    const float4 wv = ((const float4*)w)[t];
    bf16x4 o;
    o[0] = (bf16)(v.x * rstd * wv.x);
    o[1] = (bf16)(v.y * rstd * wv.y);
    o[2] = (bf16)(v.z * rstd * wv.z);
    o[3] = (bf16)(v.w * rstd * wv.w);
    ((bf16x4*)(y + row * D_))[t] = o;
}

// ---------------------------------------------------------------------------
// Chunked fused liquid-tanh + PLIF scan (warm-up contraction; see R1 notes).
// ---------------------------------------------------------------------------
#define SCAN_C  16
#define SCAN_L  (T_ / SCAN_C)   // 128
#define SCAN_W  64
#define SCAN_PF 8

template <int N, int W0>
__device__ __forceinline__ void scan_body(const uint32_t* __restrict__ p,
                                          bf16* __restrict__ o, const int ts,
                                          const float pdec, const float om,
                                          const float th) {
    uint32_t buf[SCAN_PF];
#pragma unroll
    for (int i = 0; i < SCAN_PF; ++i) buf[i] = p[(size_t)i * D_];
    float h = 0.0f, v = 0.0f;
#pragma unroll 8
    for (int k = 0; k < N; ++k) {
        const uint32_t w = buf[k & (SCAN_PF - 1)];
        if (k + SCAN_PF < N) buf[k & (SCAN_PF - 1)] = p[(size_t)(k + SCAN_PF) * D_];
        const float a  = __builtin_bit_cast(float, w << 16);
        const float bb = __builtin_bit_cast(float, w & 0xffff0000u);
        const float xv = fmaf(a, h, bb);
        const float e2 = __expf(2.0f * xv);
        h = 1.0f - __fdividef(2.0f, 1.0f + e2);          // tanh(xv)
        const float vpre = fmaf(pdec, v, om * h);
        const float s = (vpre > th) ? 1.0f : 0.0f;
        v = vpre - s * th;
        if (k >= W0) o[(size_t)(ts + k) * D_] = (bf16)(s + h);
    }
}

__global__ __launch_bounds__(256) void scan_kernel(const uint32_t* __restrict__ ABp,
                                                   const float* __restrict__ log_tau,
                                                   const float* __restrict__ thr,
                                                   bf16* __restrict__ sp) {
    const int g = blockIdx.x * 256 + threadIdx.x;   // 0 .. B_*SCAN_C*D_-1
    const int d = g & (D_ - 1);
    const int bc = g >> 10;
    const int b = bc >> 4;                 // / SCAN_C
    const int c = bc & (SCAN_C - 1);
    const float pdec = __expf(-__expf(-log_tau[d]));   // exp(-1/exp(log_tau))
    const float om = 1.0f - pdec;
    const float th = thr[d];
    const int t0 = c * SCAN_L;
    const uint32_t* base = ABp + (size_t)b * (T_ * D_) + d;
    bf16* o = sp + (size_t)b * (T_ * D_) + d;
    if (c == 0) {
        scan_body<SCAN_L, 0>(base, o, 0, pdec, om, th);
    } else {
        const int ts = t0 - SCAN_W;
        scan_body<SCAN_L + SCAN_W, SCAN_W>(base + (size_t)ts * D_, o, ts, pdec, om, th);
    }
}

// ---------------------------------------------------------------------------
// (Dual-)GEMM: C_i[M,N] = A[M,K] @ W_i[N,K]^T for i < NB, fused epilogue.
// 128x128x32 tile, 256 threads (4 waves, 2x2), 16x16x32 bf16 MFMA, 4x4/wave.
// LDS layout is XOR-swizzled: the 8-elem column group cg of row r lives at
// cg ^ (r&3). Staging applies the swizzle by permuting the GLOBAL source
// column per lane (LDS dest of global_load_lds is fixed lane*16); fragment
// reads apply the same XOR. Balances LDS bank groups in every 32-lane phase.
// MODE 0: delta/b   -> pack bf16(A_t) | bf16(b_t)<<16 into u32 out
// MODE 1: syn/gate  -> out = x + syn*sigmoid(gate)   (fp32)
// MODE 2: ffn g/u   -> out = silu(g)*u               (bf16)
// MODE 3: ffn down  -> out = x1 + acc                (fp32), NB=1
// ---------------------------------------------------------------------------
template <int NB, int MODE>
__global__ __launch_bounds__(256, 2) void gemm_kernel(
    const bf16* __restrict__ A, const bf16* __restrict__ W1, const bf16* __restrict__ W2,
    const int M, const int N, const int K,
    const float* __restrict__ b1, const float* __restrict__ b2,
    const float* __restrict__ extra, void* __restrict__ outp) {
    __shared__ bf16 As[128 * 32];
    __shared__ bf16 Bs[NB][128 * 32];

    const int tid = threadIdx.x;
    const int wave = tid >> 6;
    const int lane = tid & 63;
    const int lane15 = lane & 15;
    const int quad = lane >> 4;
    const int m0 = blockIdx.y * 128;
    const int n0 = blockIdx.x * 128;
    const int wm = (wave >> 1) * 64;
    const int wn = (wave & 1) * 64;

    f32x4 acc[NB][4][4] = {};

    // staging: each wave covers 32 rows (2 chunks of 16); lane -> (row, 8-col grp)
    const int srow = lane >> 2;                              // 0..15
    const int scol = (((lane & 3) ^ (srow & 3)) * 8);        // swizzled source col
    const bf16* gA = A + (size_t)(m0 + wave * 32 + srow) * K + scol;
    const bf16* gW[2];
    gW[0] = W1 + (size_t)(n0 + wave * 32 + srow) * K + scol;
    if (NB > 1) gW[1] = W2 + (size_t)(n0 + wave * 32 + srow) * K + scol;

    bf16* lA = As + (wave * 32) * 32;

    // fragment-read swizzle: col-group quad -> quad ^ (row&3); row&3 == lane15&3
    const int rq = (quad ^ (lane15 & 3)) * 8;

    for (int k0 = 0; k0 < K; k0 += 32) {
        __builtin_amdgcn_global_load_lds(CAST_GLB(gA + k0),            CAST_LDS(lA),            16, 0, 0);
        __builtin_amdgcn_global_load_lds(CAST_GLB(gA + k0 + 16 * K),   CAST_LDS(lA + 16 * 32),  16, 0, 0);
#pragma unroll
        for (int nb = 0; nb < NB; ++nb) {
            bf16* lB = &Bs[nb][(wave * 32) * 32];
            __builtin_amdgcn_global_load_lds(CAST_GLB(gW[nb] + k0),          CAST_LDS(lB),           16, 0, 0);
            __builtin_amdgcn_global_load_lds(CAST_GLB(gW[nb] + k0 + 16 * K), CAST_LDS(lB + 16 * 32), 16, 0, 0);
        }
        __syncthreads();   // drains vmcnt -> LDS tiles complete

        bf16x8 af[4];
#pragma unroll
        for (int i = 0; i < 4; ++i)
            af[i] = *(const bf16x8*)(As + (wm + i * 16 + lane15) * 32 + rq);
#pragma unroll
        for (int nb = 0; nb < NB; ++nb) {
#pragma unroll
            for (int j = 0; j < 4; ++j) {
                const bf16x8 bfj = *(const bf16x8*)(&Bs[nb][(wn + j * 16 + lane15) * 32 + rq]);
#pragma unroll
                for (int i = 0; i < 4; ++i)
                    acc[nb][i][j] = __builtin_amdgcn_mfma_f32_16x16x32_bf16(af[i], bfj, acc[nb][i][j], 0, 0, 0);
            }
        }
        __syncthreads();   // all waves done reading before next overwrite
    }

    // epilogue: D[row=quad*4+r][col=lane15] per 16x16 tile (verified layout)
#pragma unroll
    for (int i = 0; i < 4; ++i) {
#pragma unroll
        for (int r = 0; r < 4; ++r) {
            const int m = m0 + wm + i * 16 + quad * 4 + r;
#pragma unroll
            for (int j = 0; j < 4; ++j) {
                const int n = n0 + wn + j * 16 + lane15;
                const size_t idx = (size_t)m * N + n;
                const float v1 = acc[0][i][j][r];
                if constexpr (MODE == 0) {
                    const float v2 = acc[1][i][j][r];
                    const float dl = v1 + b1[n];
                    const float spv = (dl > 20.0f) ? dl : log1pf(__expf(dl));   // softplus
                    const float bv = spv * (v2 + b2[n]);
                    const float av = __expf(-spv * __expf(extra[n]));           // extra = A_log
                    const uint32_t pa = (uint32_t)__builtin_bit_cast(unsigned short, (bf16)av);
                    const uint32_t pb = (uint32_t)__builtin_bit_cast(unsigned short, (bf16)bv);
                    ((uint32_t*)outp)[idx] = pa | (pb << 16);
                } else if constexpr (MODE == 1) {
                    const float v2 = acc[1][i][j][r];
                    const float syn = v1 + b1[n];
                    const float z = v2 + b2[n];
                    const float gate = 1.0f / (1.0f + __expf(-z));
                    ((float*)outp)[idx] = extra[idx] + syn * gate;              // extra = x
                } else if constexpr (MODE == 2) {
                    const float v2 = acc[1][i][j][r];
                    const float sg = v1 / (1.0f + __expf(-v1));                 // silu
                    ((bf16*)outp)[idx] = (bf16)(sg * v2);
                } else {
                    ((float*)outp)[idx] = extra[idx] + v1;                      // extra = x1
                }
            }
        }
    }
}

// ---------------------------------------------------------------------------
extern "C" void kernel_launch(void* const* d_in, const int* in_sizes, int n_in,
                              void* d_out, int out_size, void* d_ws, size_t ws_size,
                              hipStream_t stream) {
    const float* x        = (const float*)d_in[0];
    const float* rms_w1   = (const float*)d_in[1];
    const float* rms_w2   = (const float*)d_in[2];
    const float* delta_w  = (const float*)d_in[3];
    const float* delta_b  = (const float*)d_in[4];
    const float* b_w      = (const float*)d_in[5];
    const float* b_b      = (const float*)d_in[6];
    const float* A_log    = (const float*)d_in[7];
    const float* log_tau  = (const float*)d_in[8];
    const float* plif_thr = (const float*)d_in[9];
    const float* syn_w    = (const float*)d_in[10];
    const float* syn_b    = (const float*)d_in[11];
    const float* gate_w   = (const float*)d_in[12];
    const float* gate_b   = (const float*)d_in[13];
    const float* ffn_g_w  = (const float*)d_in[14];
    const float* ffn_u_w  = (const float*)d_in[15];
    const float* ffn_d_w  = (const float*)d_in[16];

    char* ws = (char*)d_ws;
    const size_t MB = 1024ull * 1024ull;
    // weights bf16: [0,32MB)
    bf16* wdelta = (bf16*)(ws + 0 * MB);
    bf16* wb     = (bf16*)(ws + 2 * MB);
    bf16* wsyn   = (bf16*)(ws + 4 * MB);
    bf16* wgate  = (bf16*)(ws + 6 * MB);
    bf16* wg     = (bf16*)(ws + 8 * MB);
    bf16* wu     = (bf16*)(ws + 16 * MB);
    bf16* wd     = (bf16*)(ws + 24 * MB);
    // phase-1 buffers (all dead before act is written):
    bf16*     y1      = (bf16*)(ws + 32 * MB);       // 32MB
    uint32_t* ABp     = (uint32_t*)(ws + 64 * MB);   // 64MB
    bf16*     spikein = (bf16*)(ws + 128 * MB);      // 32MB
    // persistent:
    float* x1 = (float*)(ws + 160 * MB);             // 64MB
    bf16*  y2 = (bf16*)(ws + 224 * MB);              // 32MB
    // act aliases the dead phase-1 region [32MB,160MB): 16384*4096*2 = 128MB
    bf16* act = (bf16*)(ws + 32 * MB);
    float* outF = (float*)d_out;

    const int DD = D_ * D_;        // 1,048,576
    const int DF = DFF_ * D_;      // 4,194,304
    const int BD = DD / 1024;      // blocks per DxD tensor
    const int BF = DF / 1024;

    // --- fused weight converts (one launch) ---
    CvtArgs ca;
    ca.s[0] = delta_w; ca.d[0] = wdelta;
    ca.s[1] = b_w;     ca.d[1] = wb;
    ca.s[2] = syn_w;   ca.d[2] = wsyn;
    ca.s[3] = gate_w;  ca.d[3] = wgate;
    ca.s[4] = ffn_g_w; ca.d[4] = wg;
    ca.s[5] = ffn_u_w; ca.d[5] = wu;
    ca.s[6] = ffn_d_w; ca.d[6] = wd;
    int acc_blk = 0;
    const int segblk[7] = {BD, BD, BD, BD, BF, BF, BF};
    for (int i = 0; i < 7; ++i) { acc_blk += segblk[i]; ca.nblk[i] = acc_blk; }
    f2bf_all_kernel<<<acc_blk, 256, 0, stream>>>(ca);

    // --- RMSNorm 1 ---
    rmsnorm_kernel<<<M_, 256, 0, stream>>>(x, rms_w1, y1);

    // --- dual GEMM: delta/b -> packed (A_t, b_t) ---
    gemm_kernel<2, 0><<<dim3(D_ / 128, M_ / 128), 256, 0, stream>>>(
        y1, wdelta, wb, M_, D_, D_, delta_b, b_b, A_log, ABp);

    // --- chunked fused liquid + PLIF scans ---
    scan_kernel<<<(B_ * SCAN_C * D_) / 256, 256, 0, stream>>>(ABp, log_tau, plif_thr, spikein);

    // --- dual GEMM: syn/gate -> x1 = x + syn*sigmoid(gate) ---
    gemm_kernel<2, 1><<<dim3(D_ / 128, M_ / 128), 256, 0, stream>>>(
        spikein, wsyn, wgate, M_, D_, D_, syn_b, gate_b, x, x1);

    // --- RMSNorm 2 ---
    rmsnorm_kernel<<<M_, 256, 0, stream>>>(x1, rms_w2, y2);

    // --- dual GEMM: ffn gate/up -> act = silu(g)*u ---
    gemm_kernel<2, 2><<<dim3(DFF_ / 128, M_ / 128), 256, 0, stream>>>(
        y2, wg, wu, M_, DFF_, D_, nullptr, nullptr, nullptr, act);

    // --- GEMM: ffn down + residual -> out ---
    gemm_kernel<1, 3><<<dim3(D_ / 128, M_ / 128), 256, 0, stream>>>(
        act, wd, nullptr, M_, D_, DFF_, nullptr, nullptr, x1, outF);
}

// Round 4
// 993.332 us; speedup vs baseline: 1.1334x; 1.1334x over previous
//
#include <hip/hip_runtime.h>
#include <stdint.h>

#define B_   8
#define T_   2048
#define D_   1024
#define DFF_ 4096
#define M_   (B_ * T_)   // 16384

typedef __bf16 bf16;
typedef bf16  bf16x8 __attribute__((ext_vector_type(8)));
typedef bf16  bf16x4 __attribute__((ext_vector_type(4)));
typedef float f32x4  __attribute__((ext_vector_type(4)));

#define CAST_LDS(p) ((__attribute__((address_space(3))) void*)(p))
#define CAST_GLB(p) ((const __attribute__((address_space(1))) void*)(p))

// ---------------------------------------------------------------------------
// Fused fp32 -> bf16 convert for all 7 weight tensors (one launch).
// ---------------------------------------------------------------------------
struct CvtArgs {
    const float* s[7];
    bf16* d[7];
    int nblk[7];   // cumulative block offsets (exclusive end)
};

__global__ __launch_bounds__(256) void f2bf_all_kernel(CvtArgs a) {
    int blk = blockIdx.x;
    int seg = 0;
#pragma unroll
    for (int i = 0; i < 7; ++i) seg += (blk >= a.nblk[i]) ? 1 : 0;
    const int base = (seg == 0) ? 0 : a.nblk[seg - 1];
    const int i = ((blk - base) * 256 + threadIdx.x) * 4;
    const float4 v = *(const float4*)(a.s[seg] + i);
    bf16x4 o;
    o[0] = (bf16)v.x; o[1] = (bf16)v.y; o[2] = (bf16)v.z; o[3] = (bf16)v.w;
    *(bf16x4*)(a.d[seg] + i) = o;
}

// ---------------------------------------------------------------------------
// RMSNorm fp32-in (one block per row, D=1024, 256 threads x float4) -> bf16
// ---------------------------------------------------------------------------
__global__ __launch_bounds__(256) void rmsnorm_kernel(const float* __restrict__ x,
                                                      const float* __restrict__ w,
                                                      bf16* __restrict__ y) {
    const size_t row = blockIdx.x;
    const int t = threadIdx.x;
    const float4 v = ((const float4*)(x + row * D_))[t];
    float ss = v.x * v.x + v.y * v.y + v.z * v.z + v.w * v.w;
#pragma unroll
    for (int off = 32; off; off >>= 1) ss += __shfl_down(ss, off);
    __shared__ float red[4];
    if ((t & 63) == 0) red[t >> 6] = ss;
    __syncthreads();
    const float total = red[0] + red[1] + red[2] + red[3];
    const float rstd = rsqrtf(total * (1.0f / (float)D_) + 1e-6f);
    const float4 wv = ((const float4*)w)[t];
    bf16x4 o;
    o[0] = (bf16)(v.x * rstd * wv.x);
    o[1] = (bf16)(v.y * rstd * wv.y);
    o[2] = (bf16)(v.z * rstd * wv.z);
    o[3] = (bf16)(v.w * rstd * wv.w);
    ((bf16x4*)(y + row * D_))[t] = o;
}

// ---------------------------------------------------------------------------
// RMSNorm bf16-in (x1 path) -> bf16 out
// ---------------------------------------------------------------------------
__global__ __launch_bounds__(256) void rmsnorm_bf_kernel(const bf16* __restrict__ x,
                                                         const float* __restrict__ w,
                                                         bf16* __restrict__ y) {
    const size_t row = blockIdx.x;
    const int t = threadIdx.x;
    const bf16x4 xv = ((const bf16x4*)(x + row * D_))[t];
    float f0 = (float)xv[0], f1 = (float)xv[1], f2 = (float)xv[2], f3 = (float)xv[3];
    float ss = f0 * f0 + f1 * f1 + f2 * f2 + f3 * f3;
#pragma unroll
    for (int off = 32; off; off >>= 1) ss += __shfl_down(ss, off);
    __shared__ float red[4];
    if ((t & 63) == 0) red[t >> 6] = ss;
    __syncthreads();
    const float total = red[0] + red[1] + red[2] + red[3];
    const float rstd = rsqrtf(total * (1.0f / (float)D_) + 1e-6f);
    const float4 wv = ((const float4*)w)[t];
    bf16x4 o;
    o[0] = (bf16)(f0 * rstd * wv.x);
    o[1] = (bf16)(f1 * rstd * wv.y);
    o[2] = (bf16)(f2 * rstd * wv.z);
    o[3] = (bf16)(f3 * rstd * wv.w);
    ((bf16x4*)(y + row * D_))[t] = o;
}

// ---------------------------------------------------------------------------
// Chunked fused liquid-tanh + PLIF scan (warm-up contraction).
// Chunk 64 + 32-step warm-up: liquid contraction e^-11, PLIF decay 1e-7.
// ---------------------------------------------------------------------------
#define SCAN_C  32
#define SCAN_L  (T_ / SCAN_C)   // 64
#define SCAN_W  32
#define SCAN_PF 8

template <int N, int W0>
__device__ __forceinline__ void scan_body(const uint32_t* __restrict__ p,
                                          bf16* __restrict__ o, const int ts,
                                          const float pdec, const float om,
                                          const float th) {
    uint32_t buf[SCAN_PF];
#pragma unroll
    for (int i = 0; i < SCAN_PF; ++i) buf[i] = p[(size_t)i * D_];
    float h = 0.0f, v = 0.0f;
#pragma unroll 8
    for (int k = 0; k < N; ++k) {
        const uint32_t w = buf[k & (SCAN_PF - 1)];
        if (k + SCAN_PF < N) buf[k & (SCAN_PF - 1)] = p[(size_t)(k + SCAN_PF) * D_];
        const float a  = __builtin_bit_cast(float, w << 16);
        const float bb = __builtin_bit_cast(float, w & 0xffff0000u);
        const float xv = fmaf(a, h, bb);
        const float e2 = __expf(2.0f * xv);
        h = 1.0f - __fdividef(2.0f, 1.0f + e2);          // tanh(xv)
        const float vpre = fmaf(pdec, v, om * h);
        const float s = (vpre > th) ? 1.0f : 0.0f;
        v = vpre - s * th;
        if (k >= W0) o[(size_t)(ts + k) * D_] = (bf16)(s + h);
    }
}

__global__ __launch_bounds__(256) void scan_kernel(const uint32_t* __restrict__ ABp,
                                                   const float* __restrict__ log_tau,
                                                   const float* __restrict__ thr,
                                                   bf16* __restrict__ sp) {
    const int g = blockIdx.x * 256 + threadIdx.x;   // 0 .. B_*SCAN_C*D_-1
    const int d = g & (D_ - 1);
    const int bc = g >> 10;
    const int b = bc / SCAN_C;
    const int c = bc % SCAN_C;
    const float pdec = __expf(-__expf(-log_tau[d]));   // exp(-1/exp(log_tau))
    const float om = 1.0f - pdec;
    const float th = thr[d];
    const int t0 = c * SCAN_L;
    const uint32_t* base = ABp + (size_t)b * (T_ * D_) + d;
    bf16* o = sp + (size_t)b * (T_ * D_) + d;
    if (c == 0) {
        scan_body<SCAN_L, 0>(base, o, 0, pdec, om, th);
    } else {
        const int ts = t0 - SCAN_W;
        scan_body<SCAN_L + SCAN_W, SCAN_W>(base + (size_t)ts * D_, o, ts, pdec, om, th);
    }
}

// ---------------------------------------------------------------------------
// (Dual-)GEMM: C_i[M,N] = A[M,K] @ W_i[N,K]^T for i < NB, fused epilogue.
// 128x128x32 tile, 256 threads (4 waves, 2x2), 16x16x32 bf16 MFMA, 4x4/wave.
// m97-style layout (no swizzle: R3 showed bank swizzle is perf-negative; the
// 2.5e7 SQ_LDS_BANK_CONFLICT is structural to b128 ops, not addressable).
// MODE 0: delta/b   -> pack bf16(A_t) | bf16(b_t)<<16 into u32 out
// MODE 1: syn/gate  -> out = x + syn*sigmoid(gate)   (bf16 out, fp32 x in)
// MODE 2: ffn g/u   -> out = silu(g)*u               (bf16)
// MODE 3: ffn down  -> out = x1 + acc                (fp32 out, bf16 x1 in)
// ---------------------------------------------------------------------------
template <int NB, int MODE>
__global__ __launch_bounds__(256, 2) void gemm_kernel(
    const bf16* __restrict__ A, const bf16* __restrict__ W1, const bf16* __restrict__ W2,
    const int M, const int N, const int K,
    const float* __restrict__ b1, const float* __restrict__ b2,
    const float* __restrict__ extra, const bf16* __restrict__ extra_bf,
    void* __restrict__ outp) {
    __shared__ bf16 As[128 * 32];
    __shared__ bf16 Bs[NB][128 * 32];

    const int tid = threadIdx.x;
    const int wave = tid >> 6;
    const int lane = tid & 63;
    const int lane15 = lane & 15;
    const int quad = lane >> 4;
    const int m0 = blockIdx.y * 128;
    const int n0 = blockIdx.x * 128;
    const int wm = (wave >> 1) * 64;
    const int wn = (wave & 1) * 64;

    f32x4 acc[NB][4][4] = {};

    // staging: each wave covers 32 rows (2 chunks of 16); lane -> (row, 8-elem col)
    const int srow = lane >> 2;          // 0..15
    const int scol = (lane & 3) * 8;     // 0,8,16,24
    const bf16* gA = A + (size_t)(m0 + wave * 32 + srow) * K + scol;
    const bf16* gW[2];
    gW[0] = W1 + (size_t)(n0 + wave * 32 + srow) * K + scol;
    if (NB > 1) gW[1] = W2 + (size_t)(n0 + wave * 32 + srow) * K + scol;

    bf16* lA = As + (wave * 32) * 32;

    for (int k0 = 0; k0 < K; k0 += 32) {
        __builtin_amdgcn_global_load_lds(CAST_GLB(gA + k0),            CAST_LDS(lA),            16, 0, 0);
        __builtin_amdgcn_global_load_lds(CAST_GLB(gA + k0 + 16 * K),   CAST_LDS(lA + 16 * 32),  16, 0, 0);
#pragma unroll
        for (int nb = 0; nb < NB; ++nb) {
            bf16* lB = &Bs[nb][(wave * 32) * 32];
            __builtin_amdgcn_global_load_lds(CAST_GLB(gW[nb] + k0),          CAST_LDS(lB),           16, 0, 0);
            __builtin_amdgcn_global_load_lds(CAST_GLB(gW[nb] + k0 + 16 * K), CAST_LDS(lB + 16 * 32), 16, 0, 0);
        }
        __syncthreads();   // drains vmcnt -> LDS tiles complete

        bf16x8 af[4];
#pragma unroll
        for (int i = 0; i < 4; ++i)
            af[i] = *(const bf16x8*)(As + (wm + i * 16 + lane15) * 32 + quad * 8);
#pragma unroll
        for (int nb = 0; nb < NB; ++nb) {
#pragma unroll
            for (int j = 0; j < 4; ++j) {
                const bf16x8 bfj = *(const bf16x8*)(&Bs[nb][(wn + j * 16 + lane15) * 32 + quad * 8]);
#pragma unroll
                for (int i = 0; i < 4; ++i)
                    acc[nb][i][j] = __builtin_amdgcn_mfma_f32_16x16x32_bf16(af[i], bfj, acc[nb][i][j], 0, 0, 0);
            }
        }
        __syncthreads();   // all waves done reading before next overwrite
    }

    // epilogue: D[row=quad*4+r][col=lane15] per 16x16 tile (verified layout)
#pragma unroll
    for (int i = 0; i < 4; ++i) {
#pragma unroll
        for (int r = 0; r < 4; ++r) {
            const int m = m0 + wm + i * 16 + quad * 4 + r;
#pragma unroll
            for (int j = 0; j < 4; ++j) {
                const int n = n0 + wn + j * 16 + lane15;
                const size_t idx = (size_t)m * N + n;
                const float v1 = acc[0][i][j][r];
                if constexpr (MODE == 0) {
                    const float v2 = acc[1][i][j][r];
                    const float dl = v1 + b1[n];
                    const float spv = (dl > 20.0f) ? dl : log1pf(__expf(dl));   // softplus
                    const float bv = spv * (v2 + b2[n]);
                    const float av = __expf(-spv * __expf(extra[n]));           // extra = A_log
                    const uint32_t pa = (uint32_t)__builtin_bit_cast(unsigned short, (bf16)av);
                    const uint32_t pb = (uint32_t)__builtin_bit_cast(unsigned short, (bf16)bv);
                    ((uint32_t*)outp)[idx] = pa | (pb << 16);
                } else if constexpr (MODE == 1) {
                    const float v2 = acc[1][i][j][r];
                    const float syn = v1 + b1[n];
                    const float z = v2 + b2[n];
                    const float gate = 1.0f / (1.0f + __expf(-z));
                    ((bf16*)outp)[idx] = (bf16)(extra[idx] + syn * gate);       // extra = x
                } else if constexpr (MODE == 2) {
                    const float v2 = acc[1][i][j][r];
                    const float sg = v1 / (1.0f + __expf(-v1));                 // silu
                    ((bf16*)outp)[idx] = (bf16)(sg * v2);
                } else {
                    ((float*)outp)[idx] = (float)extra_bf[idx] + v1;            // extra_bf = x1
                }
            }
        }
    }
}

// ---------------------------------------------------------------------------
extern "C" void kernel_launch(void* const* d_in, const int* in_sizes, int n_in,
                              void* d_out, int out_size, void* d_ws, size_t ws_size,
                              hipStream_t stream) {
    const float* x        = (const float*)d_in[0];
    const float* rms_w1   = (const float*)d_in[1];
    const float* rms_w2   = (const float*)d_in[2];
    const float* delta_w  = (const float*)d_in[3];
    const float* delta_b  = (const float*)d_in[4];
    const float* b_w      = (const float*)d_in[5];
    const float* b_b      = (const float*)d_in[6];
    const float* A_log    = (const float*)d_in[7];
    const float* log_tau  = (const float*)d_in[8];
    const float* plif_thr = (const float*)d_in[9];
    const float* syn_w    = (const float*)d_in[10];
    const float* syn_b    = (const float*)d_in[11];
    const float* gate_w   = (const float*)d_in[12];
    const float* gate_b   = (const float*)d_in[13];
    const float* ffn_g_w  = (const float*)d_in[14];
    const float* ffn_u_w  = (const float*)d_in[15];
    const float* ffn_d_w  = (const float*)d_in[16];

    char* ws = (char*)d_ws;
    const size_t MB = 1024ull * 1024ull;
    // weights bf16: [0,32MB)
    bf16* wdelta = (bf16*)(ws + 0 * MB);
    bf16* wb     = (bf16*)(ws + 2 * MB);
    bf16* wsyn   = (bf16*)(ws + 4 * MB);
    bf16* wgate  = (bf16*)(ws + 6 * MB);
    bf16* wg     = (bf16*)(ws + 8 * MB);
    bf16* wu     = (bf16*)(ws + 16 * MB);
    bf16* wd     = (bf16*)(ws + 24 * MB);
    // phase-1 buffers (all dead before act is written):
    bf16*     y1      = (bf16*)(ws + 32 * MB);       // 32MB
    uint32_t* ABp     = (uint32_t*)(ws + 64 * MB);   // 64MB
    bf16*     spikein = (bf16*)(ws + 128 * MB);      // 32MB
    // persistent:
    bf16* x1 = (bf16*)(ws + 160 * MB);               // 32MB (bf16 now)
    bf16* y2 = (bf16*)(ws + 224 * MB);               // 32MB
    // act aliases the dead phase-1 region [32MB,160MB): 16384*4096*2 = 128MB
    bf16* act = (bf16*)(ws + 32 * MB);
    float* outF = (float*)d_out;

    const int DD = D_ * D_;        // 1,048,576
    const int DF = DFF_ * D_;      // 4,194,304
    const int BD = DD / 1024;      // blocks per DxD tensor
    const int BF = DF / 1024;

    // --- fused weight converts (one launch) ---
    CvtArgs ca;
    ca.s[0] = delta_w; ca.d[0] = wdelta;
    ca.s[1] = b_w;     ca.d[1] = wb;
    ca.s[2] = syn_w;   ca.d[2] = wsyn;
    ca.s[3] = gate_w;  ca.d[3] = wgate;
    ca.s[4] = ffn_g_w; ca.d[4] = wg;
    ca.s[5] = ffn_u_w; ca.d[5] = wu;
    ca.s[6] = ffn_d_w; ca.d[6] = wd;
    int acc_blk = 0;
    const int segblk[7] = {BD, BD, BD, BD, BF, BF, BF};
    for (int i = 0; i < 7; ++i) { acc_blk += segblk[i]; ca.nblk[i] = acc_blk; }
    f2bf_all_kernel<<<acc_blk, 256, 0, stream>>>(ca);

    // --- RMSNorm 1 ---
    rmsnorm_kernel<<<M_, 256, 0, stream>>>(x, rms_w1, y1);

    // --- dual GEMM: delta/b -> packed (A_t, b_t) ---
    gemm_kernel<2, 0><<<dim3(D_ / 128, M_ / 128), 256, 0, stream>>>(
        y1, wdelta, wb, M_, D_, D_, delta_b, b_b, A_log, nullptr, ABp);

    // --- chunked fused liquid + PLIF scans ---
    scan_kernel<<<(B_ * SCAN_C * D_) / 256, 256, 0, stream>>>(ABp, log_tau, plif_thr, spikein);

    // --- dual GEMM: syn/gate -> x1 = x + syn*sigmoid(gate) (bf16) ---
    gemm_kernel<2, 1><<<dim3(D_ / 128, M_ / 128), 256, 0, stream>>>(
        spikein, wsyn, wgate, M_, D_, D_, syn_b, gate_b, x, nullptr, x1);

    // --- RMSNorm 2 (bf16 in) ---
    rmsnorm_bf_kernel<<<M_, 256, 0, stream>>>(x1, rms_w2, y2);

    // --- dual GEMM: ffn gate/up -> act = silu(g)*u ---
    gemm_kernel<2, 2><<<dim3(DFF_ / 128, M_ / 128), 256, 0, stream>>>(
        y2, wg, wu, M_, DFF_, D_, nullptr, nullptr, nullptr, nullptr, act);

    // --- GEMM: ffn down + residual -> out ---
    gemm_kernel<1, 3><<<dim3(D_ / 128, M_ / 128), 256, 0, stream>>>(
        act, wd, nullptr, M_, D_, DFF_, nullptr, nullptr, nullptr, x1, outF);
}

// Round 5
// 947.458 us; speedup vs baseline: 1.1882x; 1.0484x over previous
//
#include <hip/hip_runtime.h>
#include <stdint.h>

#define B_   8
#define T_   2048
#define D_   1024
#define DFF_ 4096
#define M_   (B_ * T_)   // 16384

typedef __bf16 bf16;
typedef bf16  bf16x8 __attribute__((ext_vector_type(8)));
typedef bf16  bf16x4 __attribute__((ext_vector_type(4)));
typedef float f32x4  __attribute__((ext_vector_type(4)));

#define CAST_LDS(p) ((__attribute__((address_space(3))) void*)(p))
#define CAST_GLB(p) ((const __attribute__((address_space(1))) void*)(p))

// ---------------------------------------------------------------------------
// Fused fp32 -> bf16 convert for all 7 weight tensors (one launch).
// ---------------------------------------------------------------------------
struct CvtArgs {
    const float* s[7];
    bf16* d[7];
    int nblk[7];   // cumulative block offsets (exclusive end)
};

__global__ __launch_bounds__(256) void f2bf_all_kernel(CvtArgs a) {
    int blk = blockIdx.x;
    int seg = 0;
#pragma unroll
    for (int i = 0; i < 7; ++i) seg += (blk >= a.nblk[i]) ? 1 : 0;
    const int base = (seg == 0) ? 0 : a.nblk[seg - 1];
    const int i = ((blk - base) * 256 + threadIdx.x) * 4;
    const float4 v = *(const float4*)(a.s[seg] + i);
    bf16x4 o;
    o[0] = (bf16)v.x; o[1] = (bf16)v.y; o[2] = (bf16)v.z; o[3] = (bf16)v.w;
    *(bf16x4*)(a.d[seg] + i) = o;
}

// ---------------------------------------------------------------------------
// RMSNorm fp32-in (one block per row, D=1024, 256 threads x float4) -> bf16
// ---------------------------------------------------------------------------
__global__ __launch_bounds__(256) void rmsnorm_kernel(const float* __restrict__ x,
                                                      const float* __restrict__ w,
                                                      bf16* __restrict__ y) {
    const size_t row = blockIdx.x;
    const int t = threadIdx.x;
    const float4 v = ((const float4*)(x + row * D_))[t];
    float ss = v.x * v.x + v.y * v.y + v.z * v.z + v.w * v.w;
#pragma unroll
    for (int off = 32; off; off >>= 1) ss += __shfl_down(ss, off);
    __shared__ float red[4];
    if ((t & 63) == 0) red[t >> 6] = ss;
    __syncthreads();
    const float total = red[0] + red[1] + red[2] + red[3];
    const float rstd = rsqrtf(total * (1.0f / (float)D_) + 1e-6f);
    const float4 wv = ((const float4*)w)[t];
    bf16x4 o;
    o[0] = (bf16)(v.x * rstd * wv.x);
    o[1] = (bf16)(v.y * rstd * wv.y);
    o[2] = (bf16)(v.z * rstd * wv.z);
    o[3] = (bf16)(v.w * rstd * wv.w);
    ((bf16x4*)(y + row * D_))[t] = o;
}

// ---------------------------------------------------------------------------
// RMSNorm bf16-in (x1 path) -> bf16 out
// ---------------------------------------------------------------------------
__global__ __launch_bounds__(256) void rmsnorm_bf_kernel(const bf16* __restrict__ x,
                                                         const float* __restrict__ w,
                                                         bf16* __restrict__ y) {
    const size_t row = blockIdx.x;
    const int t = threadIdx.x;
    const bf16x4 xv = ((const bf16x4*)(x + row * D_))[t];
    float f0 = (float)xv[0], f1 = (float)xv[1], f2 = (float)xv[2], f3 = (float)xv[3];
    float ss = f0 * f0 + f1 * f1 + f2 * f2 + f3 * f3;
#pragma unroll
    for (int off = 32; off; off >>= 1) ss += __shfl_down(ss, off);
    __shared__ float red[4];
    if ((t & 63) == 0) red[t >> 6] = ss;
    __syncthreads();
    const float total = red[0] + red[1] + red[2] + red[3];
    const float rstd = rsqrtf(total * (1.0f / (float)D_) + 1e-6f);
    const float4 wv = ((const float4*)w)[t];
    bf16x4 o;
    o[0] = (bf16)(f0 * rstd * wv.x);
    o[1] = (bf16)(f1 * rstd * wv.y);
    o[2] = (bf16)(f2 * rstd * wv.z);
    o[3] = (bf16)(f3 * rstd * wv.w);
    ((bf16x4*)(y + row * D_))[t] = o;
}

// ---------------------------------------------------------------------------
// Chunked fused liquid-tanh + PLIF scan (warm-up contraction).
// Chunk 64 + 32-step warm-up: liquid contraction e^-11, PLIF decay 1e-7.
// ---------------------------------------------------------------------------
#define SCAN_C  32
#define SCAN_L  (T_ / SCAN_C)   // 64
#define SCAN_W  32
#define SCAN_PF 8

template <int N, int W0>
__device__ __forceinline__ void scan_body(const uint32_t* __restrict__ p,
                                          bf16* __restrict__ o, const int ts,
                                          const float pdec, const float om,
                                          const float th) {
    uint32_t buf[SCAN_PF];
#pragma unroll
    for (int i = 0; i < SCAN_PF; ++i) buf[i] = p[(size_t)i * D_];
    float h = 0.0f, v = 0.0f;
#pragma unroll 8
    for (int k = 0; k < N; ++k) {
        const uint32_t w = buf[k & (SCAN_PF - 1)];
        if (k + SCAN_PF < N) buf[k & (SCAN_PF - 1)] = p[(size_t)(k + SCAN_PF) * D_];
        const float a  = __builtin_bit_cast(float, w << 16);
        const float bb = __builtin_bit_cast(float, w & 0xffff0000u);
        const float xv = fmaf(a, h, bb);
        const float e2 = __expf(2.0f * xv);
        h = 1.0f - __fdividef(2.0f, 1.0f + e2);          // tanh(xv)
        const float vpre = fmaf(pdec, v, om * h);
        const float s = (vpre > th) ? 1.0f : 0.0f;
        v = vpre - s * th;
        if (k >= W0) o[(size_t)(ts + k) * D_] = (bf16)(s + h);
    }
}

__global__ __launch_bounds__(256) void scan_kernel(const uint32_t* __restrict__ ABp,
                                                   const float* __restrict__ log_tau,
                                                   const float* __restrict__ thr,
                                                   bf16* __restrict__ sp) {
    const int g = blockIdx.x * 256 + threadIdx.x;   // 0 .. B_*SCAN_C*D_-1
    const int d = g & (D_ - 1);
    const int bc = g >> 10;
    const int b = bc / SCAN_C;
    const int c = bc % SCAN_C;
    const float pdec = __expf(-__expf(-log_tau[d]));   // exp(-1/exp(log_tau))
    const float om = 1.0f - pdec;
    const float th = thr[d];
    const int t0 = c * SCAN_L;
    const uint32_t* base = ABp + (size_t)b * (T_ * D_) + d;
    bf16* o = sp + (size_t)b * (T_ * D_) + d;
    if (c == 0) {
        scan_body<SCAN_L, 0>(base, o, 0, pdec, om, th);
    } else {
        const int ts = t0 - SCAN_W;
        scan_body<SCAN_L + SCAN_W, SCAN_W>(base + (size_t)ts * D_, o, ts, pdec, om, th);
    }
}

// ---------------------------------------------------------------------------
// (Dual-)GEMM: C_i[M,N] = A[M,K] @ W_i[N,K]^T for i < NB, fused epilogue.
// 128x128 tile, BK=64 as TWO 128x32 half-tiles sharing one barrier pair
// (halves barrier-drain frequency; staging + fragment addressing identical
// to the verified BK=32 pattern). 256 threads (4 waves, 2x2), 16x16x32 bf16
// MFMA, 4x4 acc/wave, 64 MFMA per wave per barrier pair.
// MODE 0: delta/b   -> pack bf16(A_t) | bf16(b_t)<<16 into u32 out
// MODE 1: syn/gate  -> out = x + syn*sigmoid(gate)   (bf16 out, fp32 x in)
// MODE 2: ffn g/u   -> out = silu(g)*u               (bf16)
// MODE 3: ffn down  -> out = x1 + acc                (fp32 out, bf16 x1 in)
// ---------------------------------------------------------------------------
template <int NB, int MODE>
__global__ __launch_bounds__(256, 2) void gemm_kernel(
    const bf16* __restrict__ A, const bf16* __restrict__ W1, const bf16* __restrict__ W2,
    const int M, const int N, const int K,
    const float* __restrict__ b1, const float* __restrict__ b2,
    const float* __restrict__ extra, const bf16* __restrict__ extra_bf,
    void* __restrict__ outp) {
    __shared__ bf16 As[2][128 * 32];
    __shared__ bf16 Bs[NB][2][128 * 32];

    const int tid = threadIdx.x;
    const int wave = tid >> 6;
    const int lane = tid & 63;
    const int lane15 = lane & 15;
    const int quad = lane >> 4;
    const int m0 = blockIdx.y * 128;
    const int n0 = blockIdx.x * 128;
    const int wm = (wave >> 1) * 64;
    const int wn = (wave & 1) * 64;

    f32x4 acc[NB][4][4] = {};

    // staging: each wave covers 32 rows (2 chunks of 16); lane -> (row, 8-elem col)
    const int srow = lane >> 2;          // 0..15
    const int scol = (lane & 3) * 8;     // 0,8,16,24
    const bf16* gA = A + (size_t)(m0 + wave * 32 + srow) * K + scol;
    const bf16* gW[2];
    gW[0] = W1 + (size_t)(n0 + wave * 32 + srow) * K + scol;
    if (NB > 1) gW[1] = W2 + (size_t)(n0 + wave * 32 + srow) * K + scol;

    const int lofs = (wave * 32) * 32;

    for (int k0 = 0; k0 < K; k0 += 64) {
#pragma unroll
        for (int h = 0; h < 2; ++h) {
            const int kh = k0 + h * 32;
            bf16* lA = &As[h][lofs];
            __builtin_amdgcn_global_load_lds(CAST_GLB(gA + kh),          CAST_LDS(lA),           16, 0, 0);
            __builtin_amdgcn_global_load_lds(CAST_GLB(gA + kh + 16 * K), CAST_LDS(lA + 16 * 32), 16, 0, 0);
#pragma unroll
            for (int nb = 0; nb < NB; ++nb) {
                bf16* lB = &Bs[nb][h][lofs];
                __builtin_amdgcn_global_load_lds(CAST_GLB(gW[nb] + kh),          CAST_LDS(lB),           16, 0, 0);
                __builtin_amdgcn_global_load_lds(CAST_GLB(gW[nb] + kh + 16 * K), CAST_LDS(lB + 16 * 32), 16, 0, 0);
            }
        }
        __syncthreads();   // one drain covers both half-tiles (12 loads/wave)

#pragma unroll
        for (int h = 0; h < 2; ++h) {
            bf16x8 af[4];
#pragma unroll
            for (int i = 0; i < 4; ++i)
                af[i] = *(const bf16x8*)(&As[h][(wm + i * 16 + lane15) * 32 + quad * 8]);
#pragma unroll
            for (int nb = 0; nb < NB; ++nb) {
#pragma unroll
                for (int j = 0; j < 4; ++j) {
                    const bf16x8 bfj = *(const bf16x8*)(&Bs[nb][h][(wn + j * 16 + lane15) * 32 + quad * 8]);
#pragma unroll
                    for (int i = 0; i < 4; ++i)
                        acc[nb][i][j] = __builtin_amdgcn_mfma_f32_16x16x32_bf16(af[i], bfj, acc[nb][i][j], 0, 0, 0);
                }
            }
        }
        __syncthreads();   // all waves done reading before next overwrite
    }

    // epilogue: D[row=quad*4+r][col=lane15] per 16x16 tile (verified layout)
#pragma unroll
    for (int i = 0; i < 4; ++i) {
#pragma unroll
        for (int r = 0; r < 4; ++r) {
            const int m = m0 + wm + i * 16 + quad * 4 + r;
#pragma unroll
            for (int j = 0; j < 4; ++j) {
                const int n = n0 + wn + j * 16 + lane15;
                const size_t idx = (size_t)m * N + n;
                const float v1 = acc[0][i][j][r];
                if constexpr (MODE == 0) {
                    const float v2 = acc[1][i][j][r];
                    const float dl = v1 + b1[n];
                    const float spv = (dl > 20.0f) ? dl : log1pf(__expf(dl));   // softplus
                    const float bv = spv * (v2 + b2[n]);
                    const float av = __expf(-spv * __expf(extra[n]));           // extra = A_log
                    const uint32_t pa = (uint32_t)__builtin_bit_cast(unsigned short, (bf16)av);
                    const uint32_t pb = (uint32_t)__builtin_bit_cast(unsigned short, (bf16)bv);
                    ((uint32_t*)outp)[idx] = pa | (pb << 16);
                } else if constexpr (MODE == 1) {
                    const float v2 = acc[1][i][j][r];
                    const float syn = v1 + b1[n];
                    const float z = v2 + b2[n];
                    const float gate = 1.0f / (1.0f + __expf(-z));
                    ((bf16*)outp)[idx] = (bf16)(extra[idx] + syn * gate);       // extra = x
                } else if constexpr (MODE == 2) {
                    const float v2 = acc[1][i][j][r];
                    const float sg = v1 / (1.0f + __expf(-v1));                 // silu
                    ((bf16*)outp)[idx] = (bf16)(sg * v2);
                } else {
                    ((float*)outp)[idx] = (float)extra_bf[idx] + v1;            // extra_bf = x1
                }
            }
        }
    }
}

// ---------------------------------------------------------------------------
extern "C" void kernel_launch(void* const* d_in, const int* in_sizes, int n_in,
                              void* d_out, int out_size, void* d_ws, size_t ws_size,
                              hipStream_t stream) {
    const float* x        = (const float*)d_in[0];
    const float* rms_w1   = (const float*)d_in[1];
    const float* rms_w2   = (const float*)d_in[2];
    const float* delta_w  = (const float*)d_in[3];
    const float* delta_b  = (const float*)d_in[4];
    const float* b_w      = (const float*)d_in[5];
    const float* b_b      = (const float*)d_in[6];
    const float* A_log    = (const float*)d_in[7];
    const float* log_tau  = (const float*)d_in[8];
    const float* plif_thr = (const float*)d_in[9];
    const float* syn_w    = (const float*)d_in[10];
    const float* syn_b    = (const float*)d_in[11];
    const float* gate_w   = (const float*)d_in[12];
    const float* gate_b   = (const float*)d_in[13];
    const float* ffn_g_w  = (const float*)d_in[14];
    const float* ffn_u_w  = (const float*)d_in[15];
    const float* ffn_d_w  = (const float*)d_in[16];

    char* ws = (char*)d_ws;
    const size_t MB = 1024ull * 1024ull;
    // weights bf16: [0,32MB)
    bf16* wdelta = (bf16*)(ws + 0 * MB);
    bf16* wb     = (bf16*)(ws + 2 * MB);
    bf16* wsyn   = (bf16*)(ws + 4 * MB);
    bf16* wgate  = (bf16*)(ws + 6 * MB);
    bf16* wg     = (bf16*)(ws + 8 * MB);
    bf16* wu     = (bf16*)(ws + 16 * MB);
    bf16* wd     = (bf16*)(ws + 24 * MB);
    // phase-1 buffers (all dead before act is written):
    bf16*     y1      = (bf16*)(ws + 32 * MB);       // 32MB
    uint32_t* ABp     = (uint32_t*)(ws + 64 * MB);   // 64MB
    bf16*     spikein = (bf16*)(ws + 128 * MB);      // 32MB
    // persistent:
    bf16* x1 = (bf16*)(ws + 160 * MB);               // 32MB (bf16)
    bf16* y2 = (bf16*)(ws + 224 * MB);               // 32MB
    // act aliases the dead phase-1 region [32MB,160MB): 16384*4096*2 = 128MB
    bf16* act = (bf16*)(ws + 32 * MB);
    float* outF = (float*)d_out;

    const int DD = D_ * D_;        // 1,048,576
    const int DF = DFF_ * D_;      // 4,194,304
    const int BD = DD / 1024;      // blocks per DxD tensor
    const int BF = DF / 1024;

    // --- fused weight converts (one launch) ---
    CvtArgs ca;
    ca.s[0] = delta_w; ca.d[0] = wdelta;
    ca.s[1] = b_w;     ca.d[1] = wb;
    ca.s[2] = syn_w;   ca.d[2] = wsyn;
    ca.s[3] = gate_w;  ca.d[3] = wgate;
    ca.s[4] = ffn_g_w; ca.d[4] = wg;
    ca.s[5] = ffn_u_w; ca.d[5] = wu;
    ca.s[6] = ffn_d_w; ca.d[6] = wd;
    int acc_blk = 0;
    const int segblk[7] = {BD, BD, BD, BD, BF, BF, BF};
    for (int i = 0; i < 7; ++i) { acc_blk += segblk[i]; ca.nblk[i] = acc_blk; }
    f2bf_all_kernel<<<acc_blk, 256, 0, stream>>>(ca);

    // --- RMSNorm 1 ---
    rmsnorm_kernel<<<M_, 256, 0, stream>>>(x, rms_w1, y1);

    // --- dual GEMM: delta/b -> packed (A_t, b_t) ---
    gemm_kernel<2, 0><<<dim3(D_ / 128, M_ / 128), 256, 0, stream>>>(
        y1, wdelta, wb, M_, D_, D_, delta_b, b_b, A_log, nullptr, ABp);

    // --- chunked fused liquid + PLIF scans ---
    scan_kernel<<<(B_ * SCAN_C * D_) / 256, 256, 0, stream>>>(ABp, log_tau, plif_thr, spikein);

    // --- dual GEMM: syn/gate -> x1 = x + syn*sigmoid(gate) (bf16) ---
    gemm_kernel<2, 1><<<dim3(D_ / 128, M_ / 128), 256, 0, stream>>>(
        spikein, wsyn, wgate, M_, D_, D_, syn_b, gate_b, x, nullptr, x1);

    // --- RMSNorm 2 (bf16 in) ---
    rmsnorm_bf_kernel<<<M_, 256, 0, stream>>>(x1, rms_w2, y2);

    // --- dual GEMM: ffn gate/up -> act = silu(g)*u ---
    gemm_kernel<2, 2><<<dim3(DFF_ / 128, M_ / 128), 256, 0, stream>>>(
        y2, wg, wu, M_, DFF_, D_, nullptr, nullptr, nullptr, nullptr, act);

    // --- GEMM: ffn down + residual -> out ---
    gemm_kernel<1, 3><<<dim3(D_ / 128, M_ / 128), 256, 0, stream>>>(
        act, wd, nullptr, M_, D_, DFF_, nullptr, nullptr, nullptr, x1, outF);
}